// Round 2
// baseline (59.172 us; speedup 1.0000x reference)
//
#include <hip/hip_runtime.h>

#define BSZ 2048
#define DIM 256
#define NB  2048          // blocks for the main sum kernel

// d_ws layout (ints): off[0..BSZ]  (exclusive prefix, off[BSZ]=N), maxlen at [BSZ+1]

// ---- Kernel A: single-block prefix scan of graph_len + global max ----
__global__ __launch_bounds__(256) void scan_kernel(const int* __restrict__ len,
                                                   int* __restrict__ ws_i)
{
    const int t = threadIdx.x;
    int loc[8];
    int run = 0, mymax = 0;
    #pragma unroll
    for (int j = 0; j < 8; ++j) {
        const int l = len[t * 8 + j];
        run += l;
        loc[j] = run;                 // inclusive within-thread prefix
        mymax = max(mymax, l);
    }

    __shared__ int s[256];
    __shared__ int smax[256];
    s[t] = run;
    smax[t] = mymax;
    __syncthreads();
    // Hillis-Steele inclusive scan over thread totals (and max-scan)
    for (int d = 1; d < 256; d <<= 1) {
        const int v = (t >= d) ? s[t - d] : 0;
        const int m = (t >= d) ? smax[t - d] : 0;
        __syncthreads();
        s[t] += v;
        smax[t] = max(smax[t], m);
        __syncthreads();
    }
    const int base = s[t] - run;      // exclusive prefix of this thread's chunk
    if (t == 0) ws_i[0] = 0;
    #pragma unroll
    for (int j = 0; j < 8; ++j) ws_i[t * 8 + j + 1] = base + loc[j];
    if (t == 255) ws_i[BSZ + 1] = smax[255];   // global max
}

// ---- Kernel B: fixed 128-row chunks, segment sum, atomic combine at seams ----
__global__ __launch_bounds__(256) void sum_kernel(const float* __restrict__ emb,
                                                  const int* __restrict__ ws_i,
                                                  float* __restrict__ out,
                                                  int N, int chunk)
{
    const int r0 = blockIdx.x * chunk;
    if (r0 >= N) return;
    const int r1 = min(r0 + chunk, N);

    const float inv_max = 1.0f / (float)ws_i[BSZ + 1];

    // binary search: largest g with off[g] <= r0
    int lo = 0, hi = BSZ - 1;
    while (lo < hi) {
        const int mid = (lo + hi + 1) >> 1;
        if (ws_i[mid] <= r0) lo = mid; else hi = mid - 1;
    }
    int g = lo;

    const int cg = threadIdx.x & 63;  // column group: floats cg*4..cg*4+3
    const int rg = threadIdx.x >> 6;  // row group 0..3
    __shared__ float4 s_part[4][64];

    int row = r0;
    while (row < r1) {
        const int seg_start = ws_i[g];
        const int seg_end_g = ws_i[g + 1];
        const int seg_end   = min(seg_end_g, r1);

        float4 acc = make_float4(0.f, 0.f, 0.f, 0.f);
        const float* base = emb + (size_t)cg * 4;
        for (int r = row + rg; r < seg_end; r += 4) {
            const float4 v = *reinterpret_cast<const float4*>(base + (size_t)r * DIM);
            acc.x += v.x; acc.y += v.y; acc.z += v.z; acc.w += v.w;
        }

        s_part[rg][cg] = acc;
        __syncthreads();
        if (rg == 0) {
            const float4 a0 = s_part[0][cg];
            const float4 a1 = s_part[1][cg];
            const float4 a2 = s_part[2][cg];
            const float4 a3 = s_part[3][cg];
            float4 r;
            r.x = (a0.x + a1.x + a2.x + a3.x) * inv_max;
            r.y = (a0.y + a1.y + a2.y + a3.y) * inv_max;
            r.z = (a0.z + a1.z + a2.z + a3.z) * inv_max;
            r.w = (a0.w + a1.w + a2.w + a3.w) * inv_max;
            float* o = out + (size_t)g * DIM + (size_t)cg * 4;
            if (seg_start >= r0 && seg_end_g <= r1) {
                // graph fully inside this chunk: no other block contributes
                *reinterpret_cast<float4*>(o) = r;
            } else {
                atomicAdd(o + 0, r.x);
                atomicAdd(o + 1, r.y);
                atomicAdd(o + 2, r.z);
                atomicAdd(o + 3, r.w);
            }
        }
        __syncthreads();   // s_part reused next segment
        row = seg_end;
        ++g;
    }
}

extern "C" void kernel_launch(void* const* d_in, const int* in_sizes, int n_in,
                              void* d_out, int out_size, void* d_ws, size_t ws_size,
                              hipStream_t stream) {
    const float* emb = (const float*)d_in[0];
    const int*   len = (const int*)d_in[1];
    float*       out = (float*)d_out;
    int*         wsi = (int*)d_ws;

    const int N = in_sizes[0] / DIM;              // total rows
    const int chunk = (N + NB - 1) / NB;          // ~128 rows per block

    hipMemsetAsync(out, 0, (size_t)out_size * sizeof(float), stream);
    scan_kernel<<<1, 256, 0, stream>>>(len, wsi);
    sum_kernel<<<NB, 256, 0, stream>>>(emb, wsi, out, N, chunk);
}

// Round 4
// 53.493 us; speedup vs baseline: 1.1062x; 1.1062x over previous
//
#include <hip/hip_runtime.h>

#define BSZ 2048
#define DIM 256

typedef float f4 __attribute__((ext_vector_type(4)));

// One block per graph. 256 threads = 4 waves; all 2048 blocks co-resident
// (8 blocks/CU x 4 waves = 32 waves/CU), so streaming is BW-shared and
// imbalance self-amortizes.
__global__ __launch_bounds__(256) void graph_mean_kernel(
    const float* __restrict__ emb,
    const int*   __restrict__ len,
    float*       __restrict__ out)
{
    const int b    = blockIdx.x;
    const int tid  = threadIdx.x;
    const int lane = tid & 63;
    const int wv   = tid >> 6;

    // ---- Phase 1: offset = sum len[0..b), plus global max(len) ----
    // 8 strided int loads per thread (len is 8 KB, L2-resident), then
    // wave shuffle-reduce (no barriers) + 4-value LDS combine (1 barrier).
    int po = 0, pm = 0;
    #pragma unroll
    for (int j = 0; j < 8; ++j) {
        const int i = tid + j * 256;
        const int l = len[i];
        po += (i < b) ? l : 0;
        pm  = max(pm, l);
    }
    #pragma unroll
    for (int d = 32; d > 0; d >>= 1) {
        po += __shfl_down(po, d);
        pm  = max(pm, __shfl_down(pm, d));
    }
    __shared__ int s_o[4];
    __shared__ int s_m[4];
    if (lane == 0) { s_o[wv] = po; s_m[wv] = pm; }
    __syncthreads();
    const int   start   = s_o[0] + s_o[1] + s_o[2] + s_o[3];
    const float inv_max = 1.0f / (float)max(max(s_m[0], s_m[1]), max(s_m[2], s_m[3]));
    const int   mylen   = len[b];

    // ---- Phase 2: segment sum, nontemporal f4 loads, 2x unroll ----
    const int cg = lane;      // columns cg*4 .. cg*4+3 (wave covers full row)
    const int rg = wv;        // row group 0..3

    f4 acc0 = {0.f, 0.f, 0.f, 0.f};
    f4 acc1 = {0.f, 0.f, 0.f, 0.f};
    const f4* base = reinterpret_cast<const f4*>(emb + (size_t)start * DIM) + cg;
    int r = rg;
    for (; r + 4 < mylen; r += 8) {
        const f4 v0 = __builtin_nontemporal_load(base + (size_t)r       * (DIM / 4));
        const f4 v1 = __builtin_nontemporal_load(base + (size_t)(r + 4) * (DIM / 4));
        acc0 += v0;
        acc1 += v1;
    }
    if (r < mylen) {
        acc0 += __builtin_nontemporal_load(base + (size_t)r * (DIM / 4));
    }
    acc0 += acc1;

    // ---- Phase 3: combine 4 row-group partials in LDS, scale, store ----
    __shared__ f4 s_part[4][64];
    s_part[rg][cg] = acc0;
    __syncthreads();

    if (rg == 0) {
        const f4 a0 = s_part[0][cg];
        const f4 a1 = s_part[1][cg];
        const f4 a2 = s_part[2][cg];
        const f4 a3 = s_part[3][cg];
        const f4 res = (a0 + a1 + a2 + a3) * inv_max;
        __builtin_nontemporal_store(res,
            reinterpret_cast<f4*>(out + (size_t)b * DIM) + cg);
    }
}

extern "C" void kernel_launch(void* const* d_in, const int* in_sizes, int n_in,
                              void* d_out, int out_size, void* d_ws, size_t ws_size,
                              hipStream_t stream) {
    const float* emb = (const float*)d_in[0];
    const int*   len = (const int*)d_in[1];
    float*       out = (float*)d_out;

    graph_mean_kernel<<<BSZ, 256, 0, stream>>>(emb, len, out);
}

// Round 5
// 50.002 us; speedup vs baseline: 1.1834x; 1.0698x over previous
//
#include <hip/hip_runtime.h>

#define BSZ 2048
#define DIM 256

typedef float f4 __attribute__((ext_vector_type(4)));

// One block per graph. 256 threads = 4 waves; all 2048 blocks co-resident
// (8 blocks/CU x 4 waves = 32 waves/CU), so streaming is BW-shared and
// imbalance self-amortizes.
// NOTE (round 4): nontemporal LOADS regressed 50->53.5us (forfeited partial
// L3 replay residency: 268MB input vs 256MB L3). Loads stay cached; only the
// write-once output store is nontemporal.
__global__ __launch_bounds__(256) void graph_mean_kernel(
    const float* __restrict__ emb,
    const int*   __restrict__ len,
    float*       __restrict__ out)
{
    const int b    = blockIdx.x;
    const int tid  = threadIdx.x;
    const int lane = tid & 63;
    const int wv   = tid >> 6;

    // ---- Phase 1: offset = sum len[0..b), plus global max(len) ----
    // 8 strided int loads per thread (len is 8 KB, L1/L2-resident), then
    // wave shuffle-reduce (no barriers) + 4-value LDS combine (1 barrier).
    int po = 0, pm = 0;
    #pragma unroll
    for (int j = 0; j < 8; ++j) {
        const int i = tid + j * 256;
        const int l = len[i];
        po += (i < b) ? l : 0;
        pm  = max(pm, l);
    }
    #pragma unroll
    for (int d = 32; d > 0; d >>= 1) {
        po += __shfl_down(po, d);
        pm  = max(pm, __shfl_down(pm, d));
    }
    __shared__ int s_o[4];
    __shared__ int s_m[4];
    if (lane == 0) { s_o[wv] = po; s_m[wv] = pm; }
    __syncthreads();
    const int   start   = s_o[0] + s_o[1] + s_o[2] + s_o[3];
    const float inv_max = 1.0f / (float)max(max(s_m[0], s_m[1]), max(s_m[2], s_m[3]));
    const int   mylen   = len[b];

    // ---- Phase 2: segment sum, cached f4 loads, 2x unroll ----
    const int cg = lane;      // columns cg*4 .. cg*4+3 (wave covers full row)
    const int rg = wv;        // row group 0..3

    f4 acc0 = {0.f, 0.f, 0.f, 0.f};
    f4 acc1 = {0.f, 0.f, 0.f, 0.f};
    const f4* base = reinterpret_cast<const f4*>(emb + (size_t)start * DIM) + cg;
    int r = rg;
    for (; r + 4 < mylen; r += 8) {
        const f4 v0 = base[(size_t)r       * (DIM / 4)];
        const f4 v1 = base[(size_t)(r + 4) * (DIM / 4)];
        acc0 += v0;
        acc1 += v1;
    }
    if (r < mylen) {
        acc0 += base[(size_t)r * (DIM / 4)];
    }
    acc0 += acc1;

    // ---- Phase 3: combine 4 row-group partials in LDS, scale, store ----
    __shared__ f4 s_part[4][64];
    s_part[rg][cg] = acc0;
    __syncthreads();

    if (rg == 0) {
        const f4 a0 = s_part[0][cg];
        const f4 a1 = s_part[1][cg];
        const f4 a2 = s_part[2][cg];
        const f4 a3 = s_part[3][cg];
        const f4 res = (a0 + a1 + a2 + a3) * inv_max;
        __builtin_nontemporal_store(res,
            reinterpret_cast<f4*>(out + (size_t)b * DIM) + cg);
    }
}

extern "C" void kernel_launch(void* const* d_in, const int* in_sizes, int n_in,
                              void* d_out, int out_size, void* d_ws, size_t ws_size,
                              hipStream_t stream) {
    const float* emb = (const float*)d_in[0];
    const int*   len = (const int*)d_in[1];
    float*       out = (float*)d_out;

    graph_mean_kernel<<<BSZ, 256, 0, stream>>>(emb, len, out);
}

// Round 6
// 47.956 us; speedup vs baseline: 1.2339x; 1.0427x over previous
//
#include <hip/hip_runtime.h>

#define BSZ 2048
#define DIM 256

typedef float f4 __attribute__((ext_vector_type(4)));

// One block per graph. 256 threads = 4 waves; all 2048 blocks co-resident
// (8 blocks/CU x 4 waves = 32 waves/CU).
// Round-4 lesson: nontemporal LOADS regressed (partial L3 replay residency);
// loads stay cached, only the write-once output store is NT.
// Round-6 change: each wave owns a CONTIGUOUS quarter of its graph's rows
// (sequential 1KB-by-1KB stream per wave -> better DRAM page locality)
// with 4 independent accumulators (deeper per-wave VMEM queue).
__global__ __launch_bounds__(256) void graph_mean_kernel(
    const float* __restrict__ emb,
    const int*   __restrict__ len,
    float*       __restrict__ out)
{
    const int b    = blockIdx.x;
    const int tid  = threadIdx.x;
    const int lane = tid & 63;
    const int wv   = tid >> 6;

    // ---- Phase 1: offset = sum len[0..b), plus global max(len) ----
    int po = 0, pm = 0;
    #pragma unroll
    for (int j = 0; j < 8; ++j) {
        const int i = tid + j * 256;
        const int l = len[i];
        po += (i < b) ? l : 0;
        pm  = max(pm, l);
    }
    #pragma unroll
    for (int d = 32; d > 0; d >>= 1) {
        po += __shfl_down(po, d);
        pm  = max(pm, __shfl_down(pm, d));
    }
    __shared__ int s_o[4];
    __shared__ int s_m[4];
    if (lane == 0) { s_o[wv] = po; s_m[wv] = pm; }
    __syncthreads();
    const int   start   = s_o[0] + s_o[1] + s_o[2] + s_o[3];
    const float inv_max = 1.0f / (float)max(max(s_m[0], s_m[1]), max(s_m[2], s_m[3]));
    const int   mylen   = len[b];

    // ---- Phase 2: segment sum. Wave wv owns rows [lo, hi) contiguous. ----
    const int lo = (mylen *  wv     ) >> 2;
    const int hi = (mylen * (wv + 1)) >> 2;

    f4 acc0 = {0.f, 0.f, 0.f, 0.f};
    f4 acc1 = {0.f, 0.f, 0.f, 0.f};
    f4 acc2 = {0.f, 0.f, 0.f, 0.f};
    f4 acc3 = {0.f, 0.f, 0.f, 0.f};
    const f4* base = reinterpret_cast<const f4*>(emb) + lane;   // lane covers cols lane*4..+3
    int r = lo;
    for (; r + 4 <= hi; r += 4) {
        const size_t row0 = (size_t)(start + r) * (DIM / 4);
        acc0 += base[row0];
        acc1 += base[row0 + 1 * (DIM / 4)];
        acc2 += base[row0 + 2 * (DIM / 4)];
        acc3 += base[row0 + 3 * (DIM / 4)];
    }
    for (; r < hi; ++r) {
        acc0 += base[(size_t)(start + r) * (DIM / 4)];
    }
    acc0 += acc1;
    acc2 += acc3;
    acc0 += acc2;

    // ---- Phase 3: combine 4 wave partials in LDS, scale, store ----
    __shared__ f4 s_part[4][64];
    s_part[wv][lane] = acc0;
    __syncthreads();

    if (wv == 0) {
        const f4 a0 = s_part[0][lane];
        const f4 a1 = s_part[1][lane];
        const f4 a2 = s_part[2][lane];
        const f4 a3 = s_part[3][lane];
        const f4 res = (a0 + a1 + a2 + a3) * inv_max;
        __builtin_nontemporal_store(res,
            reinterpret_cast<f4*>(out + (size_t)b * DIM) + lane);
    }
}

extern "C" void kernel_launch(void* const* d_in, const int* in_sizes, int n_in,
                              void* d_out, int out_size, void* d_ws, size_t ws_size,
                              hipStream_t stream) {
    const float* emb = (const float*)d_in[0];
    const int*   len = (const int*)d_in[1];
    float*       out = (float*)d_out;

    graph_mean_kernel<<<BSZ, 256, 0, stream>>>(emb, len, out);
}

// Round 7
// 45.924 us; speedup vs baseline: 1.2885x; 1.0443x over previous
//
#include <hip/hip_runtime.h>

#define BSZ 2048
#define DIM 256
#define NT_CUTOFF 256   // blocks [0, NT_CUTOFF) use nontemporal loads (~33.6 MB)
                        // so the remaining ~235 MB of emb fits in the 256 MB L3
                        // and survives across graph replays (cache partitioning).

typedef float f4 __attribute__((ext_vector_type(4)));

// One block per graph. 256 threads = 4 waves; all 2048 blocks co-resident.
// R4 lesson: NT on ALL loads regressed (forfeits cross-replay L3 residency).
// R6 lesson: contiguous per-wave row streams (1KB/instr, sequential) 50->48us.
// R7: partial-NT cache partitioning — input is 268.4MB vs 256MB L3 (cyclic
// overflow = thrash); bypassing L3 for a 34MB slice lets the rest stay hot.
__global__ __launch_bounds__(256) void graph_mean_kernel(
    const float* __restrict__ emb,
    const int*   __restrict__ len,
    float*       __restrict__ out)
{
    const int b    = blockIdx.x;
    const int tid  = threadIdx.x;
    const int lane = tid & 63;
    const int wv   = tid >> 6;

    // ---- Phase 1: offset = sum len[0..b), plus global max(len) ----
    int po = 0, pm = 0;
    #pragma unroll
    for (int j = 0; j < 8; ++j) {
        const int i = tid + j * 256;
        const int l = len[i];
        po += (i < b) ? l : 0;
        pm  = max(pm, l);
    }
    #pragma unroll
    for (int d = 32; d > 0; d >>= 1) {
        po += __shfl_down(po, d);
        pm  = max(pm, __shfl_down(pm, d));
    }
    __shared__ int s_o[4];
    __shared__ int s_m[4];
    if (lane == 0) { s_o[wv] = po; s_m[wv] = pm; }
    __syncthreads();
    const int   start   = s_o[0] + s_o[1] + s_o[2] + s_o[3];
    const float inv_max = 1.0f / (float)max(max(s_m[0], s_m[1]), max(s_m[2], s_m[3]));
    const int   mylen   = len[b];

    // ---- Phase 2: segment sum. Wave wv owns rows [lo, hi) contiguous. ----
    const int lo = (mylen *  wv     ) >> 2;
    const int hi = (mylen * (wv + 1)) >> 2;

    f4 acc0 = {0.f, 0.f, 0.f, 0.f};
    f4 acc1 = {0.f, 0.f, 0.f, 0.f};
    f4 acc2 = {0.f, 0.f, 0.f, 0.f};
    f4 acc3 = {0.f, 0.f, 0.f, 0.f};
    const f4* base = reinterpret_cast<const f4*>(emb) + lane;   // lane = cols lane*4..+3
    int r = lo;
    if (b < NT_CUTOFF) {
        // L3-bypass slice: keep the rest of emb resident across replays.
        for (; r + 4 <= hi; r += 4) {
            const size_t row0 = (size_t)(start + r) * (DIM / 4);
            acc0 += __builtin_nontemporal_load(base + row0);
            acc1 += __builtin_nontemporal_load(base + row0 + 1 * (DIM / 4));
            acc2 += __builtin_nontemporal_load(base + row0 + 2 * (DIM / 4));
            acc3 += __builtin_nontemporal_load(base + row0 + 3 * (DIM / 4));
        }
        for (; r < hi; ++r) {
            acc0 += __builtin_nontemporal_load(base + (size_t)(start + r) * (DIM / 4));
        }
    } else {
        for (; r + 4 <= hi; r += 4) {
            const size_t row0 = (size_t)(start + r) * (DIM / 4);
            acc0 += base[row0];
            acc1 += base[row0 + 1 * (DIM / 4)];
            acc2 += base[row0 + 2 * (DIM / 4)];
            acc3 += base[row0 + 3 * (DIM / 4)];
        }
        for (; r < hi; ++r) {
            acc0 += base[(size_t)(start + r) * (DIM / 4)];
        }
    }
    acc0 += acc1;
    acc2 += acc3;
    acc0 += acc2;

    // ---- Phase 3: combine 4 wave partials in LDS, scale, store ----
    __shared__ f4 s_part[4][64];
    s_part[wv][lane] = acc0;
    __syncthreads();

    if (wv == 0) {
        const f4 a0 = s_part[0][lane];
        const f4 a1 = s_part[1][lane];
        const f4 a2 = s_part[2][lane];
        const f4 a3 = s_part[3][lane];
        const f4 res = (a0 + a1 + a2 + a3) * inv_max;
        __builtin_nontemporal_store(res,
            reinterpret_cast<f4*>(out + (size_t)b * DIM) + lane);
    }
}

extern "C" void kernel_launch(void* const* d_in, const int* in_sizes, int n_in,
                              void* d_out, int out_size, void* d_ws, size_t ws_size,
                              hipStream_t stream) {
    const float* emb = (const float*)d_in[0];
    const int*   len = (const int*)d_in[1];
    float*       out = (float*)d_out;

    graph_mean_kernel<<<BSZ, 256, 0, stream>>>(emb, len, out);
}